// Round 1
// baseline (804.736 us; speedup 1.0000x reference)
//
#include <hip/hip_runtime.h>

// Problem constants (from reference setup_inputs / OUT_H, OUT_W)
#define BATCH  16
#define HIN    384
#define WIN    384
#define CH     64
#define OUTH   224
#define OUTW   224

// 16 output pixels per 256-thread block; 16 lanes (x float4) cover the 64 channels.
#define PIX_PER_BLOCK 16
#define BLOCKS_PER_IMG ((OUTH * OUTW) / PIX_PER_BLOCK)   // 50176/16 = 3136

__global__ __launch_bounds__(256) void bilinear_proj_kernel(
    const float* __restrict__ X,      // (B, HIN, WIN, CH)
    const float* __restrict__ Tm,     // (B, 9)
    float* __restrict__ out)          // (B, OUTH, OUTW, CH)
{
    const int lane       = threadIdx.x & 15;   // channel group: 4 floats each
    const int pixInBlock = threadIdx.x >> 4;

    // b derived from blockIdx only -> block-uniform -> scalar transform loads
    const int b          = blockIdx.x / BLOCKS_PER_IMG;
    const int blkInImg   = blockIdx.x % BLOCKS_PER_IMG;
    const int pInImg     = blkInImg * PIX_PER_BLOCK + pixInBlock;
    const int oy         = pInImg / OUTW;
    const int ox         = pInImg % OUTW;

    // regular grid in [-1,1], linspace with N points: step = 2/(N-1)
    const float xc = -1.0f + (float)ox * (2.0f / (float)(OUTW - 1));
    const float yc = -1.0f + (float)oy * (2.0f / (float)(OUTH - 1));

    const float* t = Tm + b * 9;
    const float t0 = t[0], t1 = t[1], t2 = t[2];
    const float t3 = t[3], t4 = t[4], t5 = t[5];
    const float t6 = t[6], t7 = t[7], t8 = t[8];

    const float s0 = t0 * xc + t1 * yc + t2;
    const float s1 = t3 * xc + t4 * yc + t5;
    const float s2 = t6 * xc + t7 * yc + t8;
    const float z  = s2 + 1e-6f;
    float x = s0 / z;
    float y = s1 / z;
    x = 0.5f * (x + 1.0f) * (float)WIN;   // note: scaled by W, not W-1 (matches ref)
    y = 0.5f * (y + 1.0f) * (float)HIN;

    // trunc toward zero (C cast == astype(int32))
    int x0 = (int)x;
    int x1 = x0 + 1;
    int y0 = (int)y;
    int y1 = y0 + 1;
    x0 = min(max(x0, 0), WIN - 1);
    x1 = min(max(x1, 0), WIN - 1);
    y0 = min(max(y0, 0), HIN - 1);
    y1 = min(max(y1, 0), HIN - 1);

    // weights from CLIPPED integer coords vs unclipped float coords (matches ref)
    const float x0f = (float)x0, x1f = (float)x1;
    const float y0f = (float)y0, y1f = (float)y1;
    const float wa = (x1f - x) * (y1f - y);
    const float wb = (x1f - x) * (y - y0f);
    const float wc = (x - x0f) * (y1f - y);
    const float wd = (x - x0f) * (y - y0f);

    const int c = lane * 4;
    const size_t imgBase = (size_t)b * (size_t)(HIN * WIN) * CH;

    const float4* pa = (const float4*)(X + imgBase + ((size_t)(y0 * WIN + x0)) * CH + c);
    const float4* pb = (const float4*)(X + imgBase + ((size_t)(y1 * WIN + x0)) * CH + c);
    const float4* pc = (const float4*)(X + imgBase + ((size_t)(y0 * WIN + x1)) * CH + c);
    const float4* pd = (const float4*)(X + imgBase + ((size_t)(y1 * WIN + x1)) * CH + c);

    const float4 va = *pa;
    const float4 vb = *pb;
    const float4 vc = *pc;
    const float4 vd = *pd;

    float4 o;
    o.x = wa * va.x + wb * vb.x + wc * vc.x + wd * vd.x;
    o.y = wa * va.y + wb * vb.y + wc * vc.y + wd * vd.y;
    o.z = wa * va.z + wb * vb.z + wc * vc.z + wd * vd.z;
    o.w = wa * va.w + wb * vb.w + wc * vc.w + wd * vd.w;

    float4* po = (float4*)(out + ((size_t)b * (OUTH * OUTW) + (size_t)pInImg) * CH + c);
    *po = o;
}

extern "C" void kernel_launch(void* const* d_in, const int* in_sizes, int n_in,
                              void* d_out, int out_size, void* d_ws, size_t ws_size,
                              hipStream_t stream) {
    const float* X  = (const float*)d_in[0];
    const float* Tm = (const float*)d_in[1];
    float* out      = (float*)d_out;

    const int nblocks = BATCH * BLOCKS_PER_IMG;  // 16 * 3136 = 50176
    bilinear_proj_kernel<<<nblocks, 256, 0, stream>>>(X, Tm, out);
}